// Round 8
// baseline (359.991 us; speedup 1.0000x reference)
//
#include <hip/hip_runtime.h>

constexpr int Uc = 100000;
constexpr int Ic = 50000;
constexpr int Nc = 150000;   // U + I
constexpr int Ec = 1000000;
constexpr int Bc = 16384;
constexpr int NBS = (Nc + 1023) / 1024;  // scan chunks = 147

typedef _Float16 h16;
union H8 { uint4 u; h16 h[8]; };

// ---------------- kernels ----------------

// zero deg (Nc uints = 37500 uint4)
__global__ void k_zero(uint4* __restrict__ deg4) {
    int i = blockIdx.x * blockDim.x + threadIdx.x;
    if (i < Nc / 4) deg4[i] = make_uint4(0u, 0u, 0u, 0u);
}

// deg count over undirected edges + (block 0) Fp[d] = F[d,:] @ pw
__global__ void k_deg2_fproj(const int* __restrict__ un, const int* __restrict__ in_,
                             unsigned* __restrict__ deg,
                             const float* __restrict__ F, const float* __restrict__ pw,
                             float* __restrict__ Fp) {
    if (blockIdx.x == 0 && threadIdx.x < 64) {
        int d = threadIdx.x;
        float s = 0.f;
#pragma unroll
        for (int j = 0; j < 64; ++j) s += F[d * 64 + j] * pw[j];
        Fp[d] = s;
    }
    int e = blockIdx.x * blockDim.x + threadIdx.x;
    if (e < Ec) {
        atomicAdd(&deg[un[e]], 1u);
        atomicAdd(&deg[in_[e]], 1u);
    }
}

// --- scan phase 1: per-1024-chunk exclusive scan of deg; also writes dinv ---
__global__ void k_scan1(const unsigned* __restrict__ deg, int* __restrict__ rowptr,
                        int* __restrict__ bsums, float* __restrict__ dinv) {
    __shared__ int sh[256];
    int tid = threadIdx.x, bid = blockIdx.x;
    int base = bid * 1024 + tid * 4;
    int v0 = (base + 0 < Nc) ? (int)deg[base + 0] : 0;
    int v1 = (base + 1 < Nc) ? (int)deg[base + 1] : 0;
    int v2 = (base + 2 < Nc) ? (int)deg[base + 2] : 0;
    int v3 = (base + 3 < Nc) ? (int)deg[base + 3] : 0;
    if (base + 0 < Nc) dinv[base + 0] = v0 ? rsqrtf((float)v0) : 0.f;
    if (base + 1 < Nc) dinv[base + 1] = v1 ? rsqrtf((float)v1) : 0.f;
    if (base + 2 < Nc) dinv[base + 2] = v2 ? rsqrtf((float)v2) : 0.f;
    if (base + 3 < Nc) dinv[base + 3] = v3 ? rsqrtf((float)v3) : 0.f;
    int s = v0 + v1 + v2 + v3;
    sh[tid] = s;
    __syncthreads();
    for (int off = 1; off < 256; off <<= 1) {
        int t = (tid >= off) ? sh[tid - off] : 0;
        __syncthreads();
        sh[tid] += t;
        __syncthreads();
    }
    int excl = sh[tid] - s;
    if (tid == 255) bsums[bid] = sh[255];
    if (base + 0 < Nc) rowptr[base + 0] = excl;
    if (base + 1 < Nc) rowptr[base + 1] = excl + v0;
    if (base + 2 < Nc) rowptr[base + 2] = excl + v0 + v1;
    if (base + 3 < Nc) rowptr[base + 3] = excl + v0 + v1 + v2;
}

// bsums scan folded in (each block redundantly scans the 147 sums in LDS)
__global__ void k_scan3(int* __restrict__ rowptr, const int* __restrict__ bsums,
                        int* __restrict__ cursor) {
    __shared__ int sh[256];
    int tid = threadIdx.x;
    int v = (tid < NBS) ? bsums[tid] : 0;
    sh[tid] = v;
    __syncthreads();
    for (int off = 1; off < 256; off <<= 1) {
        int t = (tid >= off) ? sh[tid - off] : 0;
        __syncthreads();
        sh[tid] += t;
        __syncthreads();
    }
    int excl = sh[tid] - v;
    __syncthreads();
    sh[tid] = excl;
    __syncthreads();
    int i = blockIdx.x * blockDim.x + threadIdx.x;
    if (i < Nc) {
        int r = rowptr[i] + sh[i >> 10];
        rowptr[i] = r;
        cursor[i] = r;
    }
    if (i == 0) rowptr[Nc] = 2 * Ec;
}

// fused: edge-weight projection + CSR scatter (both directions, same coef)
__global__ void k_build(const int* __restrict__ un, const int* __restrict__ in_,
                        const float* __restrict__ ef, const float* __restrict__ Fp,
                        const float* __restrict__ pb, const float* __restrict__ dinv,
                        int* __restrict__ cursor, int2* __restrict__ csr) {
    int t = blockIdx.x * blockDim.x + threadIdx.x;
    int e = t >> 4, l = t & 15;
    if (e >= Ec) return;
    float4 f = reinterpret_cast<const float4*>(ef)[(size_t)e * 16 + l];
    float4 w = reinterpret_cast<const float4*>(Fp)[l];
    float s = f.x * w.x + f.y * w.y + f.z * w.z + f.w * w.w;
    s += __shfl_xor(s, 8, 16);
    s += __shfl_xor(s, 4, 16);
    s += __shfl_xor(s, 2, 16);
    s += __shfl_xor(s, 1, 16);
    if (l == 0 || l == 8) {
        int uu = un[e], ii = in_[e];
        float c = dinv[uu] * dinv[ii] * (s + pb[0]);
        if (l == 0) {
            int pos = atomicAdd(&cursor[ii], 1);
            csr[pos] = make_int2(uu, __float_as_int(c));
        } else {
            int pos = atomicAdd(&cursor[uu], 1);
            csr[pos] = make_int2(ii, __float_as_int(c));
        }
    }
}

// convert concat(Gu,Gi) f32 -> xin fp16 (8 fp16 per thread = uint4)
__global__ void k_xin(const float* __restrict__ Gu, const float* __restrict__ Gi,
                      uint4* __restrict__ xin) {
    int t = blockIdx.x * blockDim.x + threadIdx.x;  // over Nc*8 octets
    if (t >= Nc * 8) return;
    const float4* g;
    int idx;
    if (t < Uc * 8) { g = reinterpret_cast<const float4*>(Gu); idx = t * 2; }
    else            { g = reinterpret_cast<const float4*>(Gi); idx = (t - Uc * 8) * 2; }
    float4 a = g[idx], b = g[idx + 1];
    H8 o;
    o.h[0] = (h16)a.x; o.h[1] = (h16)a.y; o.h[2] = (h16)a.z; o.h[3] = (h16)a.w;
    o.h[4] = (h16)b.x; o.h[5] = (h16)b.y; o.h[6] = (h16)b.z; o.h[7] = (h16)b.w;
    xin[t] = o.u;
}

// gather propagation over fp16 rows, 8 lanes x uint4 per row, 4x ILP.
// Covers dst rows [n0, n1).
__global__ void k_gprop(const int* __restrict__ rowptr, const int2* __restrict__ csr,
                        const uint4* __restrict__ x, uint4* __restrict__ xn,
                        int n0, int n1) {
    int t = blockIdx.x * blockDim.x + threadIdx.x;
    int n = n0 + (t >> 3), l = t & 7;
    if (n >= n1) return;
    int e0 = rowptr[n], e1 = rowptr[n + 1];
    float acc[8] = {0.f, 0.f, 0.f, 0.f, 0.f, 0.f, 0.f, 0.f};
    int e = e0;
    for (; e + 4 <= e1; e += 4) {
        int2 s0 = csr[e], s1 = csr[e + 1], s2 = csr[e + 2], s3 = csr[e + 3];
        H8 v0, v1, v2, v3;
        v0.u = x[s0.x * 8 + l];
        v1.u = x[s1.x * 8 + l];
        v2.u = x[s2.x * 8 + l];
        v3.u = x[s3.x * 8 + l];
        float c0 = __int_as_float(s0.y), c1 = __int_as_float(s1.y);
        float c2 = __int_as_float(s2.y), c3 = __int_as_float(s3.y);
#pragma unroll
        for (int j = 0; j < 8; ++j)
            acc[j] += c0 * (float)v0.h[j] + c1 * (float)v1.h[j]
                    + c2 * (float)v2.h[j] + c3 * (float)v3.h[j];
    }
    for (; e < e1; ++e) {
        int2 sc = csr[e];
        float c = __int_as_float(sc.y);
        H8 v; v.u = x[sc.x * 8 + l];
#pragma unroll
        for (int j = 0; j < 8; ++j) acc[j] += c * (float)v.h[j];
    }
    H8 o;
#pragma unroll
    for (int j = 0; j < 8; ++j) o.h[j] = (h16)acc[j];
    xn[n * 8 + l] = o.u;
}

// fused batch-side: acc = x0 + a1 x1 + a2 x2 + a3 (A x2), then dot.
// 8 lanes per (user,item) pair; lane j covers dims [8j, 8j+8).
__global__ void k_final(const float* __restrict__ Gu, const float* __restrict__ Gi,
                        const uint4* __restrict__ x1, const uint4* __restrict__ x2,
                        const int* __restrict__ rowptr, const int2* __restrict__ csr,
                        const int* __restrict__ users, const int* __restrict__ items,
                        float* __restrict__ out) {
    int t = blockIdx.x * blockDim.x + threadIdx.x;
    int wid = t >> 3, j8 = t & 7;
    if (wid >= Bc) return;
    int un = users[wid];
    int in_ = Uc + items[wid];

    float a2[2][8];
#pragma unroll
    for (int side = 0; side < 2; ++side) {
        int n = side ? in_ : un;
        const float4* g = side ? reinterpret_cast<const float4*>(Gi)
                               : reinterpret_cast<const float4*>(Gu);
        int gi = (side ? (n - Uc) : n) * 16 + 2 * j8;
        float4 ba = g[gi], bb = g[gi + 1];
        H8 h1, h2;
        h1.u = x1[(size_t)n * 8 + j8];
        h2.u = x2[(size_t)n * 8 + j8];
        float a[8];
        a[0] = ba.x; a[1] = ba.y; a[2] = ba.z; a[3] = ba.w;
        a[4] = bb.x; a[5] = bb.y; a[6] = bb.z; a[7] = bb.w;
#pragma unroll
        for (int j = 0; j < 8; ++j)
            a[j] += 0.5f * (float)h1.h[j] + (1.f / 3.f) * (float)h2.h[j];

        float su[8] = {0.f, 0.f, 0.f, 0.f, 0.f, 0.f, 0.f, 0.f};
        int e0 = rowptr[n], e1 = rowptr[n + 1];
        int e = e0;
        for (; e + 4 <= e1; e += 4) {
            int2 s0 = csr[e], s1 = csr[e + 1], s2 = csr[e + 2], s3 = csr[e + 3];
            H8 v0, v1, v2, v3;
            v0.u = x2[(size_t)s0.x * 8 + j8];
            v1.u = x2[(size_t)s1.x * 8 + j8];
            v2.u = x2[(size_t)s2.x * 8 + j8];
            v3.u = x2[(size_t)s3.x * 8 + j8];
            float c0 = __int_as_float(s0.y), c1 = __int_as_float(s1.y);
            float c2 = __int_as_float(s2.y), c3 = __int_as_float(s3.y);
#pragma unroll
            for (int j = 0; j < 8; ++j)
                su[j] += c0 * (float)v0.h[j] + c1 * (float)v1.h[j]
                       + c2 * (float)v2.h[j] + c3 * (float)v3.h[j];
        }
        for (; e < e1; ++e) {
            int2 sc = csr[e];
            float c = __int_as_float(sc.y);
            H8 v; v.u = x2[(size_t)sc.x * 8 + j8];
#pragma unroll
            for (int j = 0; j < 8; ++j) su[j] += c * (float)v.h[j];
        }
#pragma unroll
        for (int j = 0; j < 8; ++j) a2[side][j] = a[j] + 0.25f * su[j];
    }

    float p = 0.f;
#pragma unroll
    for (int j = 0; j < 8; ++j) p += a2[0][j] * a2[1][j];
    p += __shfl_xor(p, 4, 8);
    p += __shfl_xor(p, 2, 8);
    p += __shfl_xor(p, 1, 8);
    if (j8 == 0) out[wid] = p;
}

// ---------------- launch ----------------

extern "C" void kernel_launch(void* const* d_in, const int* in_sizes, int n_in,
                              void* d_out, int out_size, void* d_ws, size_t ws_size,
                              hipStream_t stream) {
    const float* Gu = (const float*)d_in[0];
    const float* Gi = (const float*)d_in[1];
    const float* F  = (const float*)d_in[2];
    const float* pw = (const float*)d_in[3];
    const float* pb = (const float*)d_in[4];
    const float* ef = (const float*)d_in[5];
    const int*   ei = (const int*)d_in[6];   // [2, 2E]
    const int* users = (const int*)d_in[7];
    const int* items = (const int*)d_in[8];
    float* out = (float*)d_out;

    float* ws = (float*)d_ws;
    float*    Fp     = ws;                          // 64
    float*    dinv   = Fp + 64;                     // N
    unsigned* deg    = (unsigned*)(dinv + Nc);      // N
    int*      rowptr = (int*)(deg + Nc);            // N+16
    int*      cursor = rowptr + (Nc + 16);          // N
    int*      bsums  = cursor + Nc;                 // 256
    int2*     csr    = (int2*)(bsums + 256);        // 2E int2 (16 MB)
    h16*      xin    = (h16*)(csr + 2 * Ec);        // N*64 fp16
    h16*      xa     = xin + (size_t)Nc * 64;       // N*64 fp16
    h16*      xb     = xa + (size_t)Nc * 64;        // N*64 fp16

    const int* un  = ei;            // user ids (first half of row 0)
    const int* in_ = ei + 2 * Ec;   // item node ids >= U (first half of row 1)

    k_zero<<<(Nc / 4 + 255) / 256, 256, 0, stream>>>((uint4*)deg);
    k_deg2_fproj<<<(Ec + 255) / 256, 256, 0, stream>>>(un, in_, deg, F, pw, Fp);
    k_scan1<<<NBS, 256, 0, stream>>>(deg, rowptr, bsums, dinv);
    k_scan3<<<(Nc + 255) / 256, 256, 0, stream>>>(rowptr, bsums, cursor);
    k_build<<<(Ec * 16) / 256, 256, 0, stream>>>(un, in_, ef, Fp, pb, dinv, cursor, csr);
    k_xin<<<(Nc * 8 + 255) / 256, 256, 0, stream>>>(Gu, Gi, (uint4*)xin);

    // layer 1: xin -> xa (user rows gather item slice, then item rows gather user slice)
    k_gprop<<<(Uc * 8 + 255) / 256, 256, 0, stream>>>(rowptr, csr, (const uint4*)xin, (uint4*)xa, 0, Uc);
    k_gprop<<<((Nc - Uc) * 8 + 255) / 256, 256, 0, stream>>>(rowptr, csr, (const uint4*)xin, (uint4*)xa, Uc, Nc);
    // layer 2: xa -> xb
    k_gprop<<<(Uc * 8 + 255) / 256, 256, 0, stream>>>(rowptr, csr, (const uint4*)xa, (uint4*)xb, 0, Uc);
    k_gprop<<<((Nc - Uc) * 8 + 255) / 256, 256, 0, stream>>>(rowptr, csr, (const uint4*)xa, (uint4*)xb, Uc, Nc);

    // fused: alpha-weighted batch accumulation + layer-3 on the fly + dot
    k_final<<<(Bc * 8 + 255) / 256, 256, 0, stream>>>(Gu, Gi, (const uint4*)xa, (const uint4*)xb,
                                                      rowptr, csr, users, items, out);
}